// Round 5
// baseline (99.147 us; speedup 1.0000x reference)
//
#include <hip/hip_runtime.h>
#include <math.h>

#define NSAMP 1024
#define DIM   64
#define NLAYER 3

#define JC 64                        // j rows per chunk (LDS tile)
#define JS (NSAMP / JC)              // 16 j-chunks
#define NT 64                        // n rows per block tile
#define RT 4                         // n rows per thread
#define NTILES (NSAMP / NT)          // 16 n-tiles
#define NBLK (NTILES * JS * NLAYER)  // 768 blocks

#define MAGICF   0x5AFE600DF1A60001ull
#define MAGIC_HI 0x5AFE600Du

// workspace layout (unsigned long long units)
#define HEAD_OFF 0                          // [3][1024][64] packed {mu,iv}
#define FLAG_OFF (NLAYER * NSAMP * DIM)     // 196608: 768 flags
#define SLOT_OFF (FLAG_OFF + NBLK)          // 768 result slots
#define WS_ULL   (SLOT_OFF + NBLK)

typedef unsigned long long u64;

// ---------------------------------------------------------------------------
// ONE dispatch, no grid barrier, no RMW atomics.
// Each block: (a) produces mu/iv for ITS 4 rows (1 value/thread) -> ws via
// relaxed agent atomics, release-flag when done; (b) stages its fr tile
// (overlaps the flag round-trip); (c) polls its ntile's 16 flags read-only;
// (d) fetches its 16 {mu,iv} via relaxed agent atomic loads (bypass
// non-coherent L2s); (e) pair loop; (f) slot store; block 0 polls slots,
// resets slots+flags, fixed-order final reduce.
__global__ __launch_bounds__(256) void ib_flag(
    const float* __restrict__ fea0, const float* __restrict__ fea1,
    const float* __restrict__ fea2, const float* __restrict__ fea3,
    const float* __restrict__ W_mu, const float* __restrict__ b_mu,
    const float* __restrict__ W_var, const float* __restrict__ b_var,
    u64* __restrict__ ws, float* __restrict__ out)
{
    const int b     = blockIdx.x;          // 0..767
    const int layer = b >> 8;
    const int sub   = b & 255;
    const int ntile = sub & 15;
    const int jc    = sub >> 4;
    const int tid   = threadIdx.x;

    const float* __restrict__ fr_p =
        (layer == 0) ? fea0 : (layer == 1) ? fea1 : fea2;   // reference
    const float* __restrict__ fs_p =
        (layer == 0) ? fea1 : (layer == 1) ? fea2 : fea3;   // student

    __shared__ float4 buf[JC][DIM / 4];    // 16 KB: fs rows, then fr tile
    __shared__ float  wsum[4];

    // ---------------- (a) produce head for rows [prow0, prow0+4) -----------
    const int prow0 = ntile * NT + jc * 4;
    {
        float* fsl = (float*)buf;
        fsl[tid] = fs_p[prow0 * DIM + tid];      // 4 contiguous rows, coalesced
    }
    __syncthreads();

    const int pcol = tid & 63;
    const int prow = prow0 + (tid >> 6);
    {
        const float4* __restrict__ fsr = ((const float4*)buf) + (tid >> 6) * (DIM / 4);
        const float4* __restrict__ wm  = (const float4*)(W_mu  + (layer * DIM + pcol) * DIM);
        const float4* __restrict__ wv  = (const float4*)(W_var + (layer * DIM + pcol) * DIM);
        float am = 0.f, av = 0.f;
#pragma unroll
        for (int k4 = 0; k4 < DIM / 4; ++k4) {
            const float4 f = fsr[k4];            // LDS broadcast (conflict-free)
            const float4 a = wm[k4];
            const float4 c = wv[k4];
            am = fmaf(f.x, a.x, am); am = fmaf(f.y, a.y, am);
            am = fmaf(f.z, a.z, am); am = fmaf(f.w, a.w, am);
            av = fmaf(f.x, c.x, av); av = fmaf(f.y, c.y, av);
            av = fmaf(f.z, c.z, av); av = fmaf(f.w, c.w, av);
        }
        const float mu = am + b_mu[layer * DIM + pcol];
        const float x  = av + b_var[layer * DIM + pcol];
        const float sp = fmaxf(x, 0.f) + log1pf(expf(-fabsf(x)));
        const float iv = 1.0f / (sp * 0.1f + 1e-6f);
        const u64 pk = ((u64)__float_as_uint(iv) << 32) | (u64)__float_as_uint(mu);
        __hip_atomic_store(&ws[HEAD_OFF + (layer * NSAMP + prow) * DIM + pcol], pk,
                           __ATOMIC_RELAXED, __HIP_MEMORY_SCOPE_AGENT);
    }
    __threadfence();
    __syncthreads();   // all head stores drained; buf reads done
    if (tid == 0)
        __hip_atomic_store(&ws[FLAG_OFF + b], MAGICF,
                           __ATOMIC_RELEASE, __HIP_MEMORY_SCOPE_AGENT);

    // ---------------- (b) stage fr j-chunk (overlaps flag round-trip) ------
    const float4* __restrict__ src = (const float4*)(fr_p + jc * JC * DIM);
#pragma unroll
    for (int t = 0; t < 4; ++t)
        ((float4*)buf)[tid + 256 * t] = src[tid + 256 * t];

    // ---------------- (c) wait for the 16 producers of my ntile ------------
    if (tid < JS) {
        u64* fl = &ws[FLAG_OFF + layer * 256 + tid * 16 + ntile];
        while (__hip_atomic_load(fl, __ATOMIC_ACQUIRE,
                                 __HIP_MEMORY_SCOPE_AGENT) != MAGICF)
            __builtin_amdgcn_s_sleep(1);
    }
    __syncthreads();   // also publishes the fr staging to the block

    // ---------------- (d) fetch my 16 {mu, iv} ------------------------------
    const int q  = tid & 15;
    const int rg = tid >> 4;
    const int d0 = q * 4;
    const int n0 = ntile * NT + rg * RT;

    float4 mu4[RT], iv4[RT];
#pragma unroll
    for (int r = 0; r < RT; ++r) {
        const u64* hp = &ws[HEAD_OFF + (layer * NSAMP + n0 + r) * DIM + d0];
        float mv[4], vv[4];
#pragma unroll
        for (int c = 0; c < 4; ++c) {
            const u64 v = __hip_atomic_load(hp + c, __ATOMIC_RELAXED,
                                            __HIP_MEMORY_SCOPE_AGENT);
            mv[c] = __uint_as_float((unsigned)v);
            vv[c] = __uint_as_float((unsigned)(v >> 32));
        }
        mu4[r] = make_float4(mv[0], mv[1], mv[2], mv[3]);
        iv4[r] = make_float4(vv[0], vv[1], vv[2], vv[3]);
    }

    // ---------------- (e) pair loop ----------------------------------------
    float4 ps[RT];
#pragma unroll
    for (int r = 0; r < RT; ++r) ps[r] = make_float4(0.f, 0.f, 0.f, 0.f);

#pragma unroll 8
    for (int j = 0; j < JC; ++j) {
        const float4 f = buf[j][q];
#pragma unroll
        for (int r = 0; r < RT; ++r) {
            ps[r].x += fabsf(f.x - mu4[r].x);
            ps[r].y += fabsf(f.y - mu4[r].y);
            ps[r].z += fabsf(f.z - mu4[r].z);
            ps[r].w += fabsf(f.w - mu4[r].w);
        }
    }

    const float inv_n = 1.0f / (float)NSAMP;
    float s = 0.f;
    if (jc == 0) {
        // positive term exactly once per (n,d)
#pragma unroll
        for (int r = 0; r < RT; ++r) {
            const float4 a = *(const float4*)(fr_p + (n0 + r) * DIM + d0);
            s += (ps[r].x * inv_n - fabsf(mu4[r].x - a.x)) * iv4[r].x;
            s += (ps[r].y * inv_n - fabsf(mu4[r].y - a.y)) * iv4[r].y;
            s += (ps[r].z * inv_n - fabsf(mu4[r].z - a.z)) * iv4[r].z;
            s += (ps[r].w * inv_n - fabsf(mu4[r].w - a.w)) * iv4[r].w;
        }
    } else {
#pragma unroll
        for (int r = 0; r < RT; ++r) {
            s += ps[r].x * inv_n * iv4[r].x;
            s += ps[r].y * inv_n * iv4[r].y;
            s += ps[r].z * inv_n * iv4[r].z;
            s += ps[r].w * inv_n * iv4[r].w;
        }
    }

    // deterministic block reduction
#pragma unroll
    for (int off = 32; off > 0; off >>= 1)
        s += __shfl_down(s, off, 64);
    if ((tid & 63) == 0) wsum[tid >> 6] = s;
    __syncthreads();

    // ---------------- (f) one contention-free slot store per block ----------
    if (tid == 0) {
        const float p = wsum[0] + wsum[1] + wsum[2] + wsum[3];
        const u64 v = ((u64)MAGIC_HI << 32) | (u64)__float_as_uint(p);
        __hip_atomic_store(&ws[SLOT_OFF + b], v, __ATOMIC_RELAXED,
                           __HIP_MEMORY_SCOPE_AGENT);
    }

    // ---------------- block 0: poll slots, reset, fixed-order reduce --------
    if (b == 0) {
        __syncthreads();
        u64 v[3];
#pragma unroll
        for (int t = 0; t < 3; ++t) {
            u64* slot = &ws[SLOT_OFF + tid + t * 256];
            for (;;) {
                const u64 x = __hip_atomic_load(slot, __ATOMIC_RELAXED,
                                                __HIP_MEMORY_SCOPE_AGENT);
                if ((unsigned)(x >> 32) == MAGIC_HI) { v[t] = x; break; }
                __builtin_amdgcn_s_sleep(1);
            }
        }
        // reset slots AND flags so no MAGIC state persists into the next call
#pragma unroll
        for (int t = 0; t < 3; ++t) {
            __hip_atomic_store(&ws[SLOT_OFF + tid + t * 256], 0ull,
                               __ATOMIC_RELAXED, __HIP_MEMORY_SCOPE_AGENT);
            __hip_atomic_store(&ws[FLAG_OFF + tid + t * 256], 0ull,
                               __ATOMIC_RELAXED, __HIP_MEMORY_SCOPE_AGENT);
        }
        float s2 = __uint_as_float((unsigned)v[0])
                 + __uint_as_float((unsigned)v[1])
                 + __uint_as_float((unsigned)v[2]);
#pragma unroll
        for (int off = 32; off > 0; off >>= 1)
            s2 += __shfl_down(s2, off, 64);
        if ((tid & 63) == 0) wsum[tid >> 6] = s2;
        __syncthreads();
        if (tid == 0)
            out[0] = (wsum[0] + wsum[1] + wsum[2] + wsum[3]) * inv_n;
    }
}

// ---------------------------------------------------------------------------
// fallback path (tiny ws): fused kernel + final reduce
__global__ __launch_bounds__(256) void ib_fused(
    const float* __restrict__ fea0, const float* __restrict__ fea1,
    const float* __restrict__ fea2, const float* __restrict__ fea3,
    const float* __restrict__ W_mu, const float* __restrict__ b_mu,
    const float* __restrict__ W_var, const float* __restrict__ b_var,
    float* __restrict__ partials)
{
    const int layer = blockIdx.y;
    const float* feas[4] = {fea0, fea1, fea2, fea3};
    const float* __restrict__ fr_p = feas[layer];
    const float* __restrict__ fs_p = feas[layer + 1];

    const int tid = threadIdx.x;
    const int d   = tid & 63;
    const int nl  = tid >> 6;
    const int n   = blockIdx.x * 4 + nl;

    __shared__ float fs[4][DIM];
    __shared__ float fr[JC][DIM];
    __shared__ float wsum[4];

    fs[nl][d] = fs_p[n * DIM + d];
    __syncthreads();

    const float* __restrict__ wm = W_mu + (layer * DIM + d) * DIM;
    const float* __restrict__ wv = W_var + (layer * DIM + d) * DIM;
    float am = 0.f, av = 0.f;
#pragma unroll
    for (int k = 0; k < DIM; ++k) {
        const float f = fs[nl][k];
        am = fmaf(f, wm[k], am);
        av = fmaf(f, wv[k], av);
    }
    const float mu = am + b_mu[layer * DIM + d];
    const float x  = av + b_var[layer * DIM + d];
    const float sp  = fmaxf(x, 0.f) + log1pf(expf(-fabsf(x)));
    const float var = sp * 0.1f + 1e-6f;

    float psum = 0.f;
    for (int j0 = 0; j0 < NSAMP; j0 += JC) {
        __syncthreads();
#pragma unroll
        for (int t = 0; t < (JC * DIM) / 256; ++t) {
            const int l = tid + t * 256;
            fr[0][l] = fr_p[j0 * DIM + l];
        }
        __syncthreads();
#pragma unroll
        for (int j = 0; j < JC; ++j)
            psum += fabsf(fr[j][d] - mu);
    }

    const float frnd = fr_p[n * DIM + d];
    float t = (psum * (1.0f / NSAMP) - fabsf(mu - frnd)) / var;

#pragma unroll
    for (int off = 32; off > 0; off >>= 1)
        t += __shfl_down(t, off, 64);
    if ((tid & 63) == 0) wsum[tid >> 6] = t;
    __syncthreads();
    if (tid == 0)
        partials[blockIdx.y * gridDim.x + blockIdx.x] =
            wsum[0] + wsum[1] + wsum[2] + wsum[3];
}

__global__ __launch_bounds__(256) void ib_final(
    const float* __restrict__ partials, int np, float scale,
    float* __restrict__ out)
{
    const int tid = threadIdx.x;
    float s = 0.f;
    for (int i = tid; i < np; i += 256) s += partials[i];
#pragma unroll
    for (int off = 32; off > 0; off >>= 1)
        s += __shfl_down(s, off, 64);
    __shared__ float wsum[4];
    if ((tid & 63) == 0) wsum[tid >> 6] = s;
    __syncthreads();
    if (tid == 0) out[0] = (wsum[0] + wsum[1] + wsum[2] + wsum[3]) * scale;
}

// ---------------------------------------------------------------------------
extern "C" void kernel_launch(void* const* d_in, const int* in_sizes, int n_in,
                              void* d_out, int out_size, void* d_ws, size_t ws_size,
                              hipStream_t stream) {
    const float* fea0  = (const float*)d_in[0];
    const float* fea1  = (const float*)d_in[1];
    const float* fea2  = (const float*)d_in[2];
    const float* fea3  = (const float*)d_in[3];
    const float* W_mu  = (const float*)d_in[4];
    const float* b_mu  = (const float*)d_in[5];
    const float* W_var = (const float*)d_in[6];
    const float* b_var = (const float*)d_in[7];
    float* out = (float*)d_out;

    if (ws_size >= WS_ULL * sizeof(u64)) {
        ib_flag<<<NBLK, 256, 0, stream>>>(
            fea0, fea1, fea2, fea3, W_mu, b_mu, W_var, b_var,
            (u64*)d_ws, out);
    } else {
        float* ws = (float*)d_ws;
        const int nblk = NSAMP / 4;
        ib_fused<<<dim3(nblk, NLAYER), 256, 0, stream>>>(
            fea0, fea1, fea2, fea3, W_mu, b_mu, W_var, b_var, ws);
        ib_final<<<1, 256, 0, stream>>>(ws, nblk * NLAYER,
                                        1.0f / (float)NSAMP, out);
    }
}

// Round 6
// 33.706 us; speedup vs baseline: 2.9415x; 2.9415x over previous
//
#include <hip/hip_runtime.h>
#include <math.h>

#define NSAMP 1024
#define DIM   64
#define NLAYER 3

#define JC 64                        // j rows per chunk (LDS tile)
#define JS (NSAMP / JC)              // 16 j-chunks
#define NT 64                        // n rows per block tile
#define RT 4                         // n rows per thread
#define NTILES (NSAMP / NT)          // 16 n-tiles
#define NBLK (NTILES * JS * NLAYER)  // 768 pair blocks

#define MAGIC_HI 0x5AFE600Du

// workspace layout (float units)
#define MU_OFF   0
#define INV_OFF  (NLAYER * NSAMP * DIM)        // 196608
#define SLOT_F   (2 * NLAYER * NSAMP * DIM)    // u64 slots start here (8B-aligned)
#define WS_REQ   ((size_t)SLOT_F * sizeof(float) + NBLK * sizeof(unsigned long long))

typedef unsigned long long u64;

// ---------------------------------------------------------------------------
// Dispatch 1: head precompute (proven round-2 kernel).
// mu[l,n,d], inv_var[l,n,d] -> ws as plain floats; kernel boundary = fence.
__global__ __launch_bounds__(256) void ib_head(
    const float* __restrict__ f1, const float* __restrict__ f2,
    const float* __restrict__ f3,
    const float* __restrict__ W_mu, const float* __restrict__ b_mu,
    const float* __restrict__ W_var, const float* __restrict__ b_var,
    float* __restrict__ ws)
{
    const int layer = blockIdx.y;
    const float* __restrict__ fs_p = (layer == 0) ? f1 : (layer == 1) ? f2 : f3;

    const int tid = threadIdx.x;
    const int d   = tid & 63;
    const int nl  = tid >> 6;
    const int n   = blockIdx.x * 4 + nl;

    __shared__ float fs[4][DIM];
    fs[nl][d] = fs_p[n * DIM + d];
    __syncthreads();

    const float4* __restrict__ wm = (const float4*)(W_mu + (layer * DIM + d) * DIM);
    const float4* __restrict__ wv = (const float4*)(W_var + (layer * DIM + d) * DIM);
    float am = 0.f, av = 0.f;
#pragma unroll
    for (int k = 0; k < DIM / 4; ++k) {
        const float4 m4 = wm[k];
        const float4 v4 = wv[k];
        const float f0 = fs[nl][k * 4 + 0];
        const float f1v = fs[nl][k * 4 + 1];
        const float f2v = fs[nl][k * 4 + 2];
        const float f3v = fs[nl][k * 4 + 3];
        am = fmaf(f0, m4.x, am); am = fmaf(f1v, m4.y, am);
        am = fmaf(f2v, m4.z, am); am = fmaf(f3v, m4.w, am);
        av = fmaf(f0, v4.x, av); av = fmaf(f1v, v4.y, av);
        av = fmaf(f2v, v4.z, av); av = fmaf(f3v, v4.w, av);
    }
    const float mu = am + b_mu[layer * DIM + d];
    const float x  = av + b_var[layer * DIM + d];
    const float sp  = fmaxf(x, 0.f) + log1pf(expf(-fabsf(x)));
    const float var = sp * 0.1f + 1e-6f;

    const int o = (layer * NSAMP + n) * DIM + d;
    ws[MU_OFF + o]  = mu;
    ws[INV_OFF + o] = 1.0f / var;
}

// ---------------------------------------------------------------------------
// Dispatch 2: pairwise + in-kernel final.
// Proven round-2 pair body; finish via round-4's contention-free scheme:
// one MAGIC slot store per block (own line, relaxed agent atomic), block 0
// polls read-only (safe: only waits for completion, never for a producer
// phase), fixed-order reduce, resets slots to 0.
__global__ __launch_bounds__(256) void ib_pairf(
    const float* __restrict__ fea0, const float* __restrict__ fea1,
    const float* __restrict__ fea2,
    const float* __restrict__ ws, u64* __restrict__ slots,
    float* __restrict__ out)
{
    const int b     = blockIdx.x;          // 0..767
    const int layer = b >> 8;
    const int sub   = b & 255;
    const int ntile = sub & 15;
    const int jc    = sub >> 4;
    const int tid   = threadIdx.x;

    const float* __restrict__ fr_p =
        (layer == 0) ? fea0 : (layer == 1) ? fea1 : fea2;

    const int q  = tid & 15;
    const int rg = tid >> 4;
    const int n0 = ntile * NT + rg * RT;
    const int d0 = q * 4;

    __shared__ float4 fr[JC][DIM / 4];   // 16 KB
    __shared__ float  wsum[4];

    // stage j-chunk (64 x 64 floats), coalesced float4
    const float4* __restrict__ src = (const float4*)(fr_p + jc * JC * DIM);
#pragma unroll
    for (int t = 0; t < 4; ++t)
        ((float4*)fr)[tid + t * 256] = src[tid + t * 256];

    // mu for my 4 rows (plain loads; written by previous dispatch)
    const float4* __restrict__ mup =
        (const float4*)(ws + MU_OFF + (layer * NSAMP + n0) * DIM + d0);
    float4 mu4[RT];
#pragma unroll
    for (int r = 0; r < RT; ++r) mu4[r] = mup[r * (DIM / 4)];

    float4 ps[RT];
#pragma unroll
    for (int r = 0; r < RT; ++r) ps[r] = make_float4(0.f, 0.f, 0.f, 0.f);

    __syncthreads();
#pragma unroll 8
    for (int j = 0; j < JC; ++j) {
        const float4 f = fr[j][q];
#pragma unroll
        for (int r = 0; r < RT; ++r) {
            ps[r].x += fabsf(f.x - mu4[r].x);
            ps[r].y += fabsf(f.y - mu4[r].y);
            ps[r].z += fabsf(f.z - mu4[r].z);
            ps[r].w += fabsf(f.w - mu4[r].w);
        }
    }

    const float4* __restrict__ ivp =
        (const float4*)(ws + INV_OFF + (layer * NSAMP + n0) * DIM + d0);
    const float inv_n = 1.0f / (float)NSAMP;
    float s = 0.f;
    if (jc == 0) {
        // positive term exactly once per (n,d)
        const float4* __restrict__ fsp = (const float4*)(fr_p + n0 * DIM + d0);
#pragma unroll
        for (int r = 0; r < RT; ++r) {
            const float4 iv = ivp[r * (DIM / 4)];
            const float4 a  = fsp[r * (DIM / 4)];
            s += (ps[r].x * inv_n - fabsf(mu4[r].x - a.x)) * iv.x;
            s += (ps[r].y * inv_n - fabsf(mu4[r].y - a.y)) * iv.y;
            s += (ps[r].z * inv_n - fabsf(mu4[r].z - a.z)) * iv.z;
            s += (ps[r].w * inv_n - fabsf(mu4[r].w - a.w)) * iv.w;
        }
    } else {
#pragma unroll
        for (int r = 0; r < RT; ++r) {
            const float4 iv = ivp[r * (DIM / 4)];
            s += ps[r].x * inv_n * iv.x;
            s += ps[r].y * inv_n * iv.y;
            s += ps[r].z * inv_n * iv.z;
            s += ps[r].w * inv_n * iv.w;
        }
    }

    // deterministic block reduction
#pragma unroll
    for (int off = 32; off > 0; off >>= 1)
        s += __shfl_down(s, off, 64);
    if ((tid & 63) == 0) wsum[tid >> 6] = s;
    __syncthreads();

    // one contention-free 8B MAGIC store per block (its own cacheline slot)
    if (tid == 0) {
        const float p = wsum[0] + wsum[1] + wsum[2] + wsum[3];
        const u64 v = ((u64)MAGIC_HI << 32) | (u64)__float_as_uint(p);
        __hip_atomic_store(&slots[b], v, __ATOMIC_RELAXED,
                           __HIP_MEMORY_SCOPE_AGENT);
    }

    // block 0: wait for ALL blocks to finish (completion-only wait — safe),
    // fixed-order reduce, reset slots so no MAGIC persists across calls.
    if (b == 0) {
        __syncthreads();
        u64 v[3];
#pragma unroll
        for (int t = 0; t < 3; ++t) {
            u64* slot = &slots[tid + t * 256];
            for (;;) {
                const u64 x = __hip_atomic_load(slot, __ATOMIC_RELAXED,
                                                __HIP_MEMORY_SCOPE_AGENT);
                if ((unsigned)(x >> 32) == MAGIC_HI) { v[t] = x; break; }
                __builtin_amdgcn_s_sleep(1);
            }
        }
#pragma unroll
        for (int t = 0; t < 3; ++t)
            __hip_atomic_store(&slots[tid + t * 256], 0ull, __ATOMIC_RELAXED,
                               __HIP_MEMORY_SCOPE_AGENT);
        float s2 = __uint_as_float((unsigned)v[0])
                 + __uint_as_float((unsigned)v[1])
                 + __uint_as_float((unsigned)v[2]);
#pragma unroll
        for (int off = 32; off > 0; off >>= 1)
            s2 += __shfl_down(s2, off, 64);
        if ((tid & 63) == 0) wsum[tid >> 6] = s2;
        __syncthreads();
        if (tid == 0)
            out[0] = (wsum[0] + wsum[1] + wsum[2] + wsum[3]) * inv_n;
    }
}

// ---------------------------------------------------------------------------
// fallback path (tiny ws): fused kernel + final reduce
__global__ __launch_bounds__(256) void ib_fused(
    const float* __restrict__ fea0, const float* __restrict__ fea1,
    const float* __restrict__ fea2, const float* __restrict__ fea3,
    const float* __restrict__ W_mu, const float* __restrict__ b_mu,
    const float* __restrict__ W_var, const float* __restrict__ b_var,
    float* __restrict__ partials)
{
    const int layer = blockIdx.y;
    const float* feas[4] = {fea0, fea1, fea2, fea3};
    const float* __restrict__ fr_p = feas[layer];
    const float* __restrict__ fs_p = feas[layer + 1];

    const int tid = threadIdx.x;
    const int d   = tid & 63;
    const int nl  = tid >> 6;
    const int n   = blockIdx.x * 4 + nl;

    __shared__ float fs[4][DIM];
    __shared__ float fr[JC][DIM];
    __shared__ float wsum[4];

    fs[nl][d] = fs_p[n * DIM + d];
    __syncthreads();

    const float* __restrict__ wm = W_mu + (layer * DIM + d) * DIM;
    const float* __restrict__ wv = W_var + (layer * DIM + d) * DIM;
    float am = 0.f, av = 0.f;
#pragma unroll
    for (int k = 0; k < DIM; ++k) {
        const float f = fs[nl][k];
        am = fmaf(f, wm[k], am);
        av = fmaf(f, wv[k], av);
    }
    const float mu = am + b_mu[layer * DIM + d];
    const float x  = av + b_var[layer * DIM + d];
    const float sp  = fmaxf(x, 0.f) + log1pf(expf(-fabsf(x)));
    const float var = sp * 0.1f + 1e-6f;

    float psum = 0.f;
    for (int j0 = 0; j0 < NSAMP; j0 += JC) {
        __syncthreads();
#pragma unroll
        for (int t = 0; t < (JC * DIM) / 256; ++t) {
            const int l = tid + t * 256;
            fr[0][l] = fr_p[j0 * DIM + l];
        }
        __syncthreads();
#pragma unroll
        for (int j = 0; j < JC; ++j)
            psum += fabsf(fr[j][d] - mu);
    }

    const float frnd = fr_p[n * DIM + d];
    float t = (psum * (1.0f / NSAMP) - fabsf(mu - frnd)) / var;

#pragma unroll
    for (int off = 32; off > 0; off >>= 1)
        t += __shfl_down(t, off, 64);
    if ((tid & 63) == 0) wsum[tid >> 6] = t;
    __syncthreads();
    if (tid == 0)
        partials[blockIdx.y * gridDim.x + blockIdx.x] =
            wsum[0] + wsum[1] + wsum[2] + wsum[3];
}

__global__ __launch_bounds__(256) void ib_final(
    const float* __restrict__ partials, int np, float scale,
    float* __restrict__ out)
{
    const int tid = threadIdx.x;
    float s = 0.f;
    for (int i = tid; i < np; i += 256) s += partials[i];
#pragma unroll
    for (int off = 32; off > 0; off >>= 1)
        s += __shfl_down(s, off, 64);
    __shared__ float wsum[4];
    if ((tid & 63) == 0) wsum[tid >> 6] = s;
    __syncthreads();
    if (tid == 0) out[0] = (wsum[0] + wsum[1] + wsum[2] + wsum[3]) * scale;
}

// ---------------------------------------------------------------------------
extern "C" void kernel_launch(void* const* d_in, const int* in_sizes, int n_in,
                              void* d_out, int out_size, void* d_ws, size_t ws_size,
                              hipStream_t stream) {
    const float* fea0  = (const float*)d_in[0];
    const float* fea1  = (const float*)d_in[1];
    const float* fea2  = (const float*)d_in[2];
    const float* fea3  = (const float*)d_in[3];
    const float* W_mu  = (const float*)d_in[4];
    const float* b_mu  = (const float*)d_in[5];
    const float* W_var = (const float*)d_in[6];
    const float* b_var = (const float*)d_in[7];
    float* out = (float*)d_out;
    float* ws  = (float*)d_ws;

    if (ws_size >= WS_REQ) {
        ib_head<<<dim3(NSAMP / 4, NLAYER), 256, 0, stream>>>(
            fea1, fea2, fea3, W_mu, b_mu, W_var, b_var, ws);
        ib_pairf<<<NBLK, 256, 0, stream>>>(
            fea0, fea1, fea2, ws, (u64*)(ws + SLOT_F), out);
    } else {
        const int nblk = NSAMP / 4;
        ib_fused<<<dim3(nblk, NLAYER), 256, 0, stream>>>(
            fea0, fea1, fea2, fea3, W_mu, b_mu, W_var, b_var, ws);
        ib_final<<<1, 256, 0, stream>>>(ws, nblk * NLAYER,
                                        1.0f / (float)NSAMP, out);
    }
}